// Round 5
// baseline (2569.993 us; speedup 1.0000x reference)
//
#include <hip/hip_runtime.h>

#define TSTEPS 784
#define BATCH  128
#define HID    256
#define WPG    8     // workgroups per group
#define BG     4     // batches per group
#define NGRP   (BATCH / BG)          // 32 groups
#define COLS   32    // hidden cols owned per WG
typedef unsigned long long u64;

// ---------------- prep: permute input (x transposed to [b][t]) ----------------
__global__ void prep_x(const float* __restrict__ in, const int* __restrict__ perm,
                       float* __restrict__ xp) {
    int b = blockIdx.x;
    for (int t = threadIdx.x; t < TSTEPS; t += blockDim.x)
        xp[b * TSTEPS + t] = in[b * TSTEPS + perm[t]];
}

// slots[parity][b][k]: hi32 = tag, lo32 = f32 bits. parity0: tag0/val0 = 0ull.
__global__ void prep_slots(u64* __restrict__ slots) {
    int i = blockIdx.x * blockDim.x + threadIdx.x;
    if (i < BATCH * HID)          slots[i] = 0ull;
    else if (i < 2 * BATCH * HID) slots[i] = 0xFFFFFFFF00000000ull;
}

// DPP-fused butterfly add: x += dpp(x). All lanes active when called.
#define DPP_ADD(x, ctl) asm("v_add_f32 %0, %1, %0 " ctl " row_mask:0xf bank_mask:0xf" \
                            : "+v"(x) : "v"(x))

// ---------------- main persistent LSTM kernel ----------------
// grid 256 x 1024, 1 WG/CU. Group g = blockIdx&31 owns batches [4g,4g+4).
// WG wgi owns 128 gate-rows (cols [32wgi,32wgi+32) x 4 gates).
// Wave = 8 rows (gate = wave>>2 uniform); lane: b2 = lane>>5 (batch pair),
// ks = lane&31 (k-slice of 8). Thread: 64 weights in VGPR, 16 accs.
// Reduce: DPP xor1/xor2/ror4/ror8 + v_permlane16_swap (all VALU, no DS).
__global__ __launch_bounds__(1024, 4) void lstm_kernel(
    const float* __restrict__ Whh, const float* __restrict__ Wih,
    const float* __restrict__ bih, const float* __restrict__ bhh,
    const float* __restrict__ xp, u64* __restrict__ slots)
{
    __shared__ float h_lds[BG * 288];        // padded: block of 8 floats + 1 pad
    __shared__ float gate_lds[4 * 132];      // [gate][b*33 + col]
    __shared__ float x_lds[BG * TSTEPS];     // 12.25 KB
    __shared__ float c_lds[BG * COLS];

    const int tid  = threadIdx.x;
    const int g    = blockIdx.x & 31;
    const int wgi  = blockIdx.x >> 5;
    const int B0   = g * BG;
    const int colbase = wgi * COLS;

    const int wave = tid >> 6;
    const int lane = tid & 63;
    const int ks   = lane & 31;        // k-slice: k in [8ks, 8ks+8)
    const int b2   = lane >> 5;        // batch pair {0,1} or {2,3}
    const int gate = wave >> 2;        // wave-uniform
    const int colw = (wave & 3) * 8;   // col base of this wave's 8 rows

    // ---- one-time: weights for rows q=0..7 (global row = gate*256+colbase+colw+q)
    float4 wA[8], wB[8];
    #pragma unroll
    for (int q = 0; q < 8; ++q) {
        const float* wp = Whh + (gate * 256 + colbase + colw + q) * HID + 8 * ks;
        wA[q] = *(const float4*)wp;
        wB[q] = *(const float4*)(wp + 4);
    }
    #define KEEP4(V) asm volatile("" : "+v"((V).x), "+v"((V).y), "+v"((V).z), "+v"((V).w))
    #pragma unroll
    for (int q = 0; q < 8; ++q) { KEEP4(wA[q]); KEEP4(wB[q]); }
    #undef KEEP4

    // ---- per-lane epilogue constants: this lane's final (row, batch) ----
    const int hl    = lane & 31;
    const int widx  = hl & 7;                       // (q2 = widx>>1, j = widx&1)
    const int q_eff = (widx >> 1) + ((hl & 16) ? 4 : 0);
    const int bsel  = 2 * b2 + (widx & 1);          // batch this lane finalizes
    const int rloc  = gate * 32 + colw + q_eff;     // local gate-row 0..127
    const int grow  = gate * 256 + colbase + colw + q_eff;
    const float bias_r = bih[grow] + bhh[grow];
    const float win_r  = Wih[grow];

    #pragma unroll
    for (int b = 0; b < BG; ++b)
        if (tid < TSTEPS) x_lds[b * TSTEPS + tid] = xp[(B0 + b) * TSTEPS + tid];
    if (tid < BG * COLS) c_lds[tid] = 0.f;
    __syncthreads();

    const int pb = tid >> 8, pk = tid & 255;
    u64* const slot0 = slots + (B0 + pb) * HID + pk;
    u64* const slot1 = slots + BATCH * HID + (B0 + pb) * HID + pk;
    const int hoff = pb * 288 + 9 * (pk >> 3) + (pk & 7);   // padded store index

    for (int t = 0; t < TSTEPS; ++t) {
        // ---- stage h_t: poll tagged slot, store into padded LDS ----
        {
            u64* sp = (t & 1) ? slot1 : slot0;
            u64 v;
            do {
                v = __hip_atomic_load(sp, __ATOMIC_RELAXED, __HIP_MEMORY_SCOPE_AGENT);
            } while ((unsigned)(v >> 32) != (unsigned)t);
            h_lds[hoff] = __uint_as_float((unsigned)v);
        }
        __syncthreads();

        // ---- dot: 4x ds_read_b128, 128 FMA into 16 accs ----
        float a[8][2];
        const float* hb0 = h_lds + (2 * b2) * 288 + 9 * ks;
        const float* hb1 = hb0 + 288;
        {
            float4 h00 = *(const float4*)(hb0);
            float4 h01 = *(const float4*)(hb0 + 4);
            #pragma unroll
            for (int q = 0; q < 8; ++q) {
                float s = wA[q].x * h00.x;
                s = fmaf(wA[q].y, h00.y, s); s = fmaf(wA[q].z, h00.z, s);
                s = fmaf(wA[q].w, h00.w, s); s = fmaf(wB[q].x, h01.x, s);
                s = fmaf(wB[q].y, h01.y, s); s = fmaf(wB[q].z, h01.z, s);
                s = fmaf(wB[q].w, h01.w, s);
                a[q][0] = s;
            }
            float4 h10 = *(const float4*)(hb1);
            float4 h11 = *(const float4*)(hb1 + 4);
            #pragma unroll
            for (int q = 0; q < 8; ++q) {
                float s = wA[q].x * h10.x;
                s = fmaf(wA[q].y, h10.y, s); s = fmaf(wA[q].z, h10.z, s);
                s = fmaf(wA[q].w, h10.w, s); s = fmaf(wB[q].x, h11.x, s);
                s = fmaf(wB[q].y, h11.y, s); s = fmaf(wB[q].z, h11.z, s);
                s = fmaf(wB[q].w, h11.w, s);
                a[q][1] = s;
            }
        }

        // ---- k-reduce: all-VALU (DPP + permlane16_swap), no DS pipe ----
        #pragma unroll
        for (int q = 0; q < 8; ++q) {
            DPP_ADD(a[q][0], "quad_perm:[1,0,3,2]");
            DPP_ADD(a[q][1], "quad_perm:[1,0,3,2]");
        }
        #pragma unroll
        for (int q = 0; q < 8; ++q) {
            DPP_ADD(a[q][0], "quad_perm:[2,3,0,1]");
            DPP_ADD(a[q][1], "quad_perm:[2,3,0,1]");
        }
        #pragma unroll
        for (int q = 0; q < 8; ++q) {
            DPP_ADD(a[q][0], "row_ror:4");
            DPP_ADD(a[q][1], "row_ror:4");
        }
        #pragma unroll
        for (int q = 0; q < 8; ++q) {
            DPP_ADD(a[q][0], "row_ror:8");
            DPP_ADD(a[q][1], "row_ror:8");
        }
        // combine the two 16-lane rows of each 32-half; after this, lanes
        // hl<16 hold rows q=0..3 full sums, hl>=16 hold rows 4..7.
        float s00, s01, s10, s11, s20, s21, s30, s31;
        #define TAIL(q, sq0, sq1) {                                           \
            asm("v_permlane16_swap_b32 %0, %1" : "+v"(a[q][0]), "+v"(a[q+4][0])); \
            sq0 = a[q][0] + a[q + 4][0];                                      \
            asm("v_permlane16_swap_b32 %0, %1" : "+v"(a[q][1]), "+v"(a[q+4][1])); \
            sq1 = a[q][1] + a[q + 4][1]; }
        TAIL(0, s00, s01) TAIL(1, s10, s11) TAIL(2, s20, s21) TAIL(3, s30, s31)
        #undef TAIL

        // ---- select this lane's (q_eff, bsel) value, finish gate, activate ----
        float t0 = (widx & 1) ? s01 : s00;
        float t1 = (widx & 1) ? s11 : s10;
        float t2 = (widx & 1) ? s21 : s20;
        float t3 = (widx & 1) ? s31 : s30;
        float u0 = (widx & 2) ? t1 : t0;
        float u1 = (widx & 2) ? t3 : t2;
        float val = (widx & 4) ? u1 : u0;
        float xv  = x_lds[bsel * TSTEPS + t];
        val = fmaf(win_r, xv, val + bias_r);
        float act = (gate == 2) ? (2.f / (1.f + __expf(-2.f * val)) - 1.f)
                                : (1.f / (1.f + __expf(-val)));
        if ((hl & 8) == 0)
            gate_lds[gate * 132 + bsel * 33 + colw + q_eff] = act;
        __syncthreads();

        // ---- c/h update (128 threads), publish tagged h ----
        if (tid < BG * COLS) {
            int b = tid >> 5, col = tid & 31;
            float iv = gate_lds[0 * 132 + b * 33 + col];
            float fv = gate_lds[1 * 132 + b * 33 + col];
            float gv = gate_lds[2 * 132 + b * 33 + col];
            float ov = gate_lds[3 * 132 + b * 33 + col];
            float cn = fmaf(fv, c_lds[tid], iv * gv);
            c_lds[tid] = cn;
            float tc = 2.f / (1.f + __expf(-2.f * cn)) - 1.f;
            float hn = ov * tc;
            u64 valw = ((u64)(unsigned)(t + 1) << 32) | (u64)__float_as_uint(hn);
            u64* dp = slots + ((t + 1) & 1) * (BATCH * HID)
                            + (B0 + b) * HID + colbase + col;
            __hip_atomic_store(dp, valw, __ATOMIC_RELAXED, __HIP_MEMORY_SCOPE_AGENT);
        }
        // no trailing barrier needed: h_lds writes of t+1 happen after this
        // point only in threads that passed the gate barrier; dot reads of
        // step t completed before it. Max inter-WG skew is 1 step (tags).
    }
}

// ---------------- final linear: out = h_784 @ lin_W.T + lin_b ----------------
__global__ void out_kernel(const u64* __restrict__ slots, const float* __restrict__ linW,
                           const float* __restrict__ linb, float* __restrict__ out) {
    __shared__ float hl[HID];
    int b = blockIdx.x;
    for (int k = threadIdx.x; k < HID; k += blockDim.x)
        hl[k] = __uint_as_float((unsigned)slots[b * HID + k]);
    __syncthreads();
    if (threadIdx.x < 10) {
        int n = threadIdx.x;
        float acc = linb[n];
        for (int k = 0; k < HID; ++k) acc = fmaf(hl[k], linW[n * HID + k], acc);
        out[b * 10 + n] = acc;
    }
}

extern "C" void kernel_launch(void* const* d_in, const int* in_sizes, int n_in,
                              void* d_out, int out_size, void* d_ws, size_t ws_size,
                              hipStream_t stream) {
    const float* inputs = (const float*)d_in[0];
    const int*   perm   = (const int*)d_in[1];
    const float* Wih    = (const float*)d_in[2];
    const float* Whh    = (const float*)d_in[3];
    const float* bih    = (const float*)d_in[4];
    const float* bhh    = (const float*)d_in[5];
    const float* linW   = (const float*)d_in[6];
    const float* linb   = (const float*)d_in[7];
    float* out = (float*)d_out;

    // d_ws layout: slots[2][128][256] u64 (512KB) | xp[128][784] f32 (401KB)
    u64*   slots = (u64*)d_ws;
    float* xp    = (float*)(slots + 2 * BATCH * HID);

    prep_x<<<BATCH, 256, 0, stream>>>(inputs, perm, xp);
    prep_slots<<<(2 * BATCH * HID + 255) / 256, 256, 0, stream>>>(slots);
    lstm_kernel<<<NGRP * WPG, 1024, 0, stream>>>(Whh, Wih, bih, bhh, xp, slots);
    out_kernel<<<BATCH, 64, 0, stream>>>(slots, linW, linb, out);
}

// Round 7
// 2473.053 us; speedup vs baseline: 1.0392x; 1.0392x over previous
//
#include <hip/hip_runtime.h>

#define TSTEPS 784
#define BATCH  128
#define HID    256
#define WPG    8     // workgroups per group
#define BG     4     // batches per group
#define NGRP   (BATCH / BG)          // 32 groups
#define COLS   32    // hidden cols owned per WG
#define RLOC   128   // local gate rows per WG (4 gates x 32 cols)
#define MAXFAST 256  // fast-poll iterations before sticky fallback
typedef unsigned long long u64;

// ---------------- prep: permute input (x transposed to [b][t]) ----------------
__global__ void prep_x(const float* __restrict__ in, const int* __restrict__ perm,
                       float* __restrict__ xp) {
    int b = blockIdx.x;
    for (int t = threadIdx.x; t < TSTEPS; t += blockDim.x)
        xp[b * TSTEPS + t] = in[b * TSTEPS + perm[t]];
}

// slots[parity][b][k]: hi32 = tag, lo32 = f32 bits. parity0: tag0/val0 = 0ull.
__global__ void prep_slots(u64* __restrict__ slots) {
    int i = blockIdx.x * blockDim.x + threadIdx.x;
    if (i < BATCH * HID)          slots[i] = 0ull;
    else if (i < 2 * BATCH * HID) slots[i] = 0xFFFFFFFF00000000ull;
}

// ---------------- main persistent LSTM kernel ----------------
// grid 256 x 1024. group g = blockIdx&31 owns batches [4g,4g+4); its 8 WGs
// (blockIdx g, g+32, ...) land on one XCD under round-robin dispatch, making
// the sc0 L2 exchange fast — but correctness NEVER depends on that:
// producers double-store (sc0 + agent-atomic), consumers watchdog-fallback
// to agent-atomic polls, so any cache behavior only changes speed.
// WG wgi = blockIdx>>5 owns cols [32wgi, 32wgi+32). thread: r = tid>>3 local
// gate-row (gate=r>>5, col=r&31), s = tid&7 k-slice of 32. 32 weights/thread
// in VGPRs (pinned), rotate-stored -> conflict-free broadcast ds_read_b128.
__global__ __launch_bounds__(1024, 4) void lstm_kernel(
    const float* __restrict__ Whh, const float* __restrict__ Wih,
    const float* __restrict__ bih, const float* __restrict__ bhh,
    const float* __restrict__ xp, u64* __restrict__ slots)
{
    __shared__ float h_lds[BG * HID];            // 4 KB staged h_t
    __shared__ float gate_lds[BG * 132];         // activated gates, padded stride
    __shared__ float x_lds[BG * TSTEPS];         // 12.25 KB
    __shared__ float c_lds[BG * COLS];
    __shared__ float bias_lds[RLOC];
    __shared__ float win_lds[RLOC];

    const int tid = threadIdx.x;
    const int g       = blockIdx.x & 31;
    const int wgi     = blockIdx.x >> 5;
    const int B0      = g * BG;
    const int colbase = wgi * COLS;

    const int r = tid >> 3;                  // local gate-row 0..127
    const int s = tid & 7;                   // k-slice
    const int gate = r >> 5;                 // wave-uniform (8 r's per wave)
    const int R = gate * 256 + colbase + (r & 31);   // global gate row

    // ---- one-time loads; rotate-store: reg d holds quad index (d+s)&7 ----
    float4 w0, w1, w2, w3, w4, w5, w6, w7;
    {
        const float4* wp = (const float4*)(Whh + R * HID + s * 32);
        w0 = wp[(0 + s) & 7]; w1 = wp[(1 + s) & 7];
        w2 = wp[(2 + s) & 7]; w3 = wp[(3 + s) & 7];
        w4 = wp[(4 + s) & 7]; w5 = wp[(5 + s) & 7];
        w6 = wp[(6 + s) & 7]; w7 = wp[(7 + s) & 7];
    }
    #define KEEP4(V) asm volatile("" : "+v"((V).x), "+v"((V).y), "+v"((V).z), "+v"((V).w))
    KEEP4(w0); KEEP4(w1); KEEP4(w2); KEEP4(w3);
    KEEP4(w4); KEEP4(w5); KEEP4(w6); KEEP4(w7);
    #undef KEEP4

    if (tid < RLOC) {
        int gr = (tid >> 5) * 256 + colbase + (tid & 31);
        bias_lds[tid] = bih[gr] + bhh[gr];
        win_lds[tid]  = Wih[gr];
    }
    #pragma unroll
    for (int b = 0; b < BG; ++b)
        if (tid < TSTEPS) x_lds[b * TSTEPS + tid] = xp[(B0 + b) * TSTEPS + tid];
    if (tid < BG * COLS) c_lds[tid] = 0.f;
    __syncthreads();

    // poll target for this thread: element (pb, pk) of the group's h
    const int pb = tid >> 8, pk = tid & 255;
    u64* const slot0 = slots + (B0 + pb) * HID + pk;               // parity 0
    u64* const slot1 = slots + BATCH * HID + (B0 + pb) * HID + pk; // parity 1

    bool fast_ok = true;   // sticky per-thread: fast L2 polling until proven stale

    for (int t = 0; t < TSTEPS; ++t) {
        // ---- stage h_t: fast sc0 poll with watchdog, else agent-atomic poll ----
        {
            u64* sp = (t & 1) ? slot1 : slot0;
            u64 v = 0;
            if (fast_ok) {
                int it = 0;
                for (;;) {
                    asm volatile("global_load_dwordx2 %0, %1, off sc0\n\t"
                                 "s_waitcnt vmcnt(0)"
                                 : "=v"(v) : "v"(sp) : "memory");
                    if ((unsigned)(v >> 32) == (unsigned)t) break;
                    if (++it >= MAXFAST) { fast_ok = false; break; }
                }
            }
            if (!fast_ok) {
                do {
                    v = __hip_atomic_load(sp, __ATOMIC_RELAXED, __HIP_MEMORY_SCOPE_AGENT);
                } while ((unsigned)(v >> 32) != (unsigned)t);
            }
            h_lds[tid] = __uint_as_float((unsigned)v);
        }
        __syncthreads();

        // ---- dot: weights in VGPRs, h via rotated broadcast ds_read_b128 ----
        float a0 = 0.f, a1 = 0.f, a2 = 0.f, a3 = 0.f;
        const float* hbase = h_lds + s * 32;
        #define DOT_STEP(d, wd)                                              \
        {                                                                    \
            int off = (((d) + s) & 7) * 4;                                   \
            float4 hq0 = *(const float4*)(hbase + off);                      \
            float4 hq1 = *(const float4*)(hbase + 256 + off);                \
            float4 hq2 = *(const float4*)(hbase + 512 + off);                \
            float4 hq3 = *(const float4*)(hbase + 768 + off);                \
            a0 = fmaf(wd.x, hq0.x, a0); a0 = fmaf(wd.y, hq0.y, a0);          \
            a0 = fmaf(wd.z, hq0.z, a0); a0 = fmaf(wd.w, hq0.w, a0);          \
            a1 = fmaf(wd.x, hq1.x, a1); a1 = fmaf(wd.y, hq1.y, a1);          \
            a1 = fmaf(wd.z, hq1.z, a1); a1 = fmaf(wd.w, hq1.w, a1);          \
            a2 = fmaf(wd.x, hq2.x, a2); a2 = fmaf(wd.y, hq2.y, a2);          \
            a2 = fmaf(wd.z, hq2.z, a2); a2 = fmaf(wd.w, hq2.w, a2);          \
            a3 = fmaf(wd.x, hq3.x, a3); a3 = fmaf(wd.y, hq3.y, a3);          \
            a3 = fmaf(wd.w, hq3.w, a3); a3 = fmaf(wd.z, hq3.z, a3);          \
        }
        DOT_STEP(0, w0) DOT_STEP(1, w1) DOT_STEP(2, w2) DOT_STEP(3, w3)
        DOT_STEP(4, w4) DOT_STEP(5, w5) DOT_STEP(6, w6) DOT_STEP(7, w7)
        #undef DOT_STEP

        // ---- k-reduce across the 8 slice-lanes (in-wave butterfly) ----
        #pragma unroll
        for (int m = 1; m < 8; m <<= 1) {
            a0 += __shfl_xor(a0, m, 64);
            a1 += __shfl_xor(a1, m, 64);
            a2 += __shfl_xor(a2, m, 64);
            a3 += __shfl_xor(a3, m, 64);
        }
        // lane s finishes batch s: bias + w_in*x, activate (gate wave-uniform)
        if (s < BG) {
            float sum = (s == 0) ? a0 : (s == 1) ? a1 : (s == 2) ? a2 : a3;
            float xv = x_lds[s * TSTEPS + t];
            float full = fmaf(win_lds[r], xv, sum + bias_lds[r]);
            float act;
            if (gate == 2) act = 2.f / (1.f + __expf(-2.f * full)) - 1.f;  // tanh
            else           act = 1.f / (1.f + __expf(-full));              // sigmoid
            gate_lds[s * 132 + r] = act;
        }
        __syncthreads();

        // ---- c/h update (128 threads), publish tagged h (double-store) ----
        if (tid < BG * COLS) {
            int b = tid >> 5, j = tid & 31;
            float iv = gate_lds[b * 132 + j];
            float fv = gate_lds[b * 132 + 32 + j];
            float gv = gate_lds[b * 132 + 64 + j];
            float ov = gate_lds[b * 132 + 96 + j];
            float cn = fmaf(fv, c_lds[tid], iv * gv);
            c_lds[tid] = cn;
            float tc = 2.f / (1.f + __expf(-2.f * cn)) - 1.f;
            float hn = ov * tc;
            u64 val = ((u64)(unsigned)(t + 1) << 32) | (u64)__float_as_uint(hn);
            u64* dp = slots + ((t + 1) & 1) * (BATCH * HID)
                            + (B0 + b) * HID + colbase + j;
            // fast store: write-through to local-XCD L2 (sc0)
            asm volatile("global_store_dwordx2 %0, %1, off sc0"
                         :: "v"(dp), "v"(val) : "memory");
            // guaranteed store: agent-scope atomic (LLC-visible). Same bytes,
            // so any ordering/writeback interleaving is value-safe.
            __hip_atomic_store(dp, val, __ATOMIC_RELAXED, __HIP_MEMORY_SCOPE_AGENT);
        }
        // no trailing barrier: all h_lds dot-reads for step t happened before
        // the gate barrier; staging of t+1 comes after it. Tag monotonicity +
        // 8B single-load atomicity make the parity overwrite safe.
    }
}

// ---------------- final linear: out = h_784 @ lin_W.T + lin_b ----------------
__global__ void out_kernel(const u64* __restrict__ slots, const float* __restrict__ linW,
                           const float* __restrict__ linb, float* __restrict__ out) {
    __shared__ float hl[HID];
    int b = blockIdx.x;
    // T=784 even -> final h is in parity-0 slots, low 32 bits
    for (int k = threadIdx.x; k < HID; k += blockDim.x)
        hl[k] = __uint_as_float((unsigned)slots[b * HID + k]);
    __syncthreads();
    if (threadIdx.x < 10) {
        int n = threadIdx.x;
        float acc = linb[n];
        for (int k = 0; k < HID; ++k) acc = fmaf(hl[k], linW[n * HID + k], acc);
        out[b * 10 + n] = acc;
    }
}

extern "C" void kernel_launch(void* const* d_in, const int* in_sizes, int n_in,
                              void* d_out, int out_size, void* d_ws, size_t ws_size,
                              hipStream_t stream) {
    const float* inputs = (const float*)d_in[0];
    const int*   perm   = (const int*)d_in[1];
    const float* Wih    = (const float*)d_in[2];
    const float* Whh    = (const float*)d_in[3];
    const float* bih    = (const float*)d_in[4];
    const float* bhh    = (const float*)d_in[5];
    const float* linW   = (const float*)d_in[6];
    const float* linb   = (const float*)d_in[7];
    float* out = (float*)d_out;

    // d_ws layout: slots[2][128][256] u64 (512KB) | xp[128][784] f32 (401KB)
    u64*   slots = (u64*)d_ws;
    float* xp    = (float*)(slots + 2 * BATCH * HID);

    prep_x<<<BATCH, 256, 0, stream>>>(inputs, perm, xp);
    prep_slots<<<(2 * BATCH * HID + 255) / 256, 256, 0, stream>>>(slots);
    lstm_kernel<<<NGRP * WPG, 1024, 0, stream>>>(Whh, Wih, bih, bhh, xp, slots);
    out_kernel<<<BATCH, 64, 0, stream>>>(slots, linW, linb, out);
}